// Round 1
// baseline (793.830 us; speedup 1.0000x reference)
//
#include <hip/hip_runtime.h>
#include <hip/hip_bf16.h>

typedef unsigned long long u64;

#define KNMS 1000      // MAX_BOX_PRE_NMS (hardcoded in reference)
#define KP   1024      // padded stride for per-pair arrays
#define KPSH 10
#define CAP  4096      // stage-2 candidate capacity (LDS)
#define FCAP 2048      // final-stage candidate capacity
#define IOU_THR 0.5f

#define NEGINF __uint_as_float(0xFF800000u)

// ---------------------------------------------------------------------------
// helpers
// ---------------------------------------------------------------------------

// Find the histogram bin containing rank `rank` counting from the TOP.
// Outputs: s_bin (boundary bin), s_gt (# elements strictly above boundary bin),
// s_total (total histogrammed), s_all (1 if total <= rank -> take everything).
__device__ __forceinline__ void find_cutoff(unsigned int* hist, int nbins,
    unsigned int* csum, int nthreads, int tid, unsigned int rank,
    unsigned int* s_bin, unsigned int* s_gt, unsigned int* s_total, int* s_all) {
  int chunk = nbins / nthreads;
  unsigned int cs = 0;
  int base = tid * chunk;
  for (int q = 0; q < chunk; q++) cs += hist[base + q];
  csum[tid] = cs;
  __syncthreads();
  if (tid == 0) {
    unsigned int total = 0;
    for (int ch = 0; ch < nthreads; ch++) total += csum[ch];
    *s_total = total;
    if (total <= rank) { *s_bin = 0u; *s_gt = 0u; *s_all = 1; }
    else {
      unsigned int acc = 0; int ch = nthreads - 1;
      while (acc + csum[ch] < rank) { acc += csum[ch]; ch--; }
      int bin = ch * chunk + chunk - 1;
      while (acc + hist[bin] < rank) { acc += hist[bin]; bin--; }
      *s_bin = (unsigned)bin; *s_gt = acc; *s_all = 0;
    }
  }
  __syncthreads();
}

// In-LDS bitonic sort, descending, 64-bit keys.
template<int N, int NT>
__device__ __forceinline__ void bitonic_desc(u64* a, int tid) {
  for (int k = 2; k <= N; k <<= 1) {
    for (int j = k >> 1; j > 0; j >>= 1) {
      for (int t = tid; t < N; t += NT) {
        int ixj = t ^ j;
        if (ixj > t) {
          u64 x = a[t], y = a[ixj];
          if (((t & k) == 0) ? (x < y) : (x > y)) { a[t] = y; a[ixj] = x; }
        }
      }
      __syncthreads();
    }
  }
}

// ---------------------------------------------------------------------------
// kernel 1: transpose classification [B,A,C] -> [B,C,A]  (C <= 127)
// ---------------------------------------------------------------------------
__global__ __launch_bounds__(256) void k_transpose(const float* __restrict__ src0,
    float* __restrict__ dst0, int A, int C) {
  __shared__ float tile[64 * 129];
  int b = blockIdx.y;
  int a0 = blockIdx.x * 64;
  const float* src = src0 + (size_t)b * A * C;
  float* dst = dst0 + (size_t)b * A * C;
  int st = C + 1;
  for (int idx = threadIdx.x; idx < 64 * C; idx += 256) {
    int al = idx / C, c = idx - al * C;
    int a = a0 + al;
    tile[al * st + c] = (a < A) ? src[(size_t)a * C + c] : 0.f;
  }
  __syncthreads();
  for (int idx = threadIdx.x; idx < 64 * C; idx += 256) {
    int c = idx >> 6, al = idx & 63;
    int a = a0 + al;
    if (a < A) dst[(size_t)c * A + a] = tile[al * st + c];
  }
}

// ---------------------------------------------------------------------------
// kernel 2: per (b,c) pair: threshold gate + stable top-KNMS (desc, low index
// first on ties) via radix-select (hist on bits>>18) + bitonic sort of keys
// key = (score_bits << 32) | ~anchor_index   (monotone for positive scores)
// ---------------------------------------------------------------------------
__global__ __launch_bounds__(512) void k_topk(
    const float* __restrict__ cls, int transposed,
    const float* __restrict__ tanch, const float* __restrict__ thr_p,
    float* __restrict__ scores_s, float* __restrict__ boxes_s,
    float* __restrict__ area_s, int* __restrict__ cnt_s,
    int A, int C) {
  int pair = blockIdx.x;
  int tid = threadIdx.x;
  int b = pair / C, c = pair - b * C;
  const float* col; int str;
  if (transposed) { col = cls + (size_t)pair * A; str = 1; }
  else            { col = cls + (size_t)b * A * C + c; str = C; }
  float thr = *thr_p;

  __shared__ union { unsigned int hist[8192]; u64 cand[CAP]; } sh;
  __shared__ unsigned int csum[512];
  __shared__ unsigned int s_b1, s_gt1, s_tot1, s_b2, s_gt2, s_tot2;
  __shared__ int s_all1, s_all2, s_mode, s_n;

  for (int i = tid; i < 8192; i += 512) sh.hist[i] = 0u;
  __syncthreads();

  // pass 1: histogram of score bits >> 18 (scores are positive: thr >= 0)
  bool vec = (str == 1) && ((A & 3) == 0);
  if (vec) {
    const float4* col4 = (const float4*)col;
    int A4 = A >> 2;
    for (int i = tid; i < A4; i += 512) {
      float4 v = col4[i];
      float vv[4] = {v.x, v.y, v.z, v.w};
#pragma unroll
      for (int q = 0; q < 4; q++)
        if (vv[q] > thr) atomicAdd(&sh.hist[__float_as_uint(vv[q]) >> 18], 1u);
    }
  } else {
    for (int a = tid; a < A; a += 512) {
      float s = col[(size_t)a * str];
      if (s > thr) atomicAdd(&sh.hist[__float_as_uint(s) >> 18], 1u);
    }
  }
  __syncthreads();
  find_cutoff(sh.hist, 8192, csum, 512, tid, KNMS, &s_b1, &s_gt1, &s_tot1, &s_all1);
  unsigned int b1 = s_b1, gt1 = s_gt1, tot = s_tot1;
  unsigned int m1 = sh.hist[b1];
  if (tid == 0) s_mode = s_all1 ? 1 : 0;
  __syncthreads();

  if (s_mode == 0 && gt1 + m1 > CAP) {
    // level-2 refine within boundary bin (rare; pathological tie pileups)
    for (int i = tid; i < 2048; i += 512) sh.hist[i] = 0u;
    __syncthreads();
    for (int a = tid; a < A; a += 512) {
      float s = col[(size_t)a * str];
      if (s > thr) {
        unsigned bits = __float_as_uint(s);
        if ((bits >> 18) == b1) atomicAdd(&sh.hist[(bits >> 7) & 2047u], 1u);
      }
    }
    __syncthreads();
    find_cutoff(sh.hist, 2048, csum, 512, tid, KNMS - gt1, &s_b2, &s_gt2, &s_tot2, &s_all2);
    if (tid == 0) s_mode = 2;
    __syncthreads();
  }
  int mode = s_mode;
  unsigned int b2v = (mode == 2 && !s_all2) ? s_b2 : 0u;

  if (tid == 0) s_n = 0;
  __syncthreads();

  // pass 2: compact candidate keys into LDS
  if (vec) {
    const float4* col4 = (const float4*)col;
    int A4 = A >> 2;
    for (int i = tid; i < A4; i += 512) {
      float4 v = col4[i];
      float vv[4] = {v.x, v.y, v.z, v.w};
#pragma unroll
      for (int q = 0; q < 4; q++) {
        float s = vv[q];
        if (s > thr) {
          unsigned bits = __float_as_uint(s);
          unsigned bin = bits >> 18;
          bool take = (mode == 1) || (mode == 0 ? (bin >= b1)
                      : (bin > b1 || (bin == b1 && ((bits >> 7) & 2047u) >= b2v)));
          if (take) {
            int pos = atomicAdd(&s_n, 1);
            if (pos < CAP)
              sh.cand[pos] = ((u64)bits << 32) | (unsigned)(~(unsigned)(i * 4 + q));
          }
        }
      }
    }
  } else {
    for (int a = tid; a < A; a += 512) {
      float s = col[(size_t)a * str];
      if (s > thr) {
        unsigned bits = __float_as_uint(s);
        unsigned bin = bits >> 18;
        bool take = (mode == 1) || (mode == 0 ? (bin >= b1)
                    : (bin > b1 || (bin == b1 && ((bits >> 7) & 2047u) >= b2v)));
        if (take) {
          int pos = atomicAdd(&s_n, 1);
          if (pos < CAP)
            sh.cand[pos] = ((u64)bits << 32) | (unsigned)(~(unsigned)a);
        }
      }
    }
  }
  __syncthreads();
  int n = s_n < CAP ? s_n : CAP;
  for (int t = tid; t < CAP; t += 512)
    if (t >= n) sh.cand[t] = 0ull;
  __syncthreads();

  bitonic_desc<CAP, 512>((u64*)sh.cand, tid);

  int n_valid = (int)tot < KNMS ? (int)tot : KNMS;
  for (int k = tid; k < KNMS; k += 512) {
    u64 key = sh.cand[k];
    float sc; float4 bx; float ar;
    if (k < n_valid && key != 0ull) {
      sc = __uint_as_float((unsigned)(key >> 32));
      unsigned a = ~(unsigned)key;
      bx = ((const float4*)tanch)[(size_t)b * A + a];
      ar = (bx.z - bx.x) * (bx.w - bx.y);
    } else {
      sc = NEGINF; bx = make_float4(0.f, 0.f, 0.f, 0.f); ar = 0.f;
    }
    scores_s[(size_t)pair * KP + k] = sc;
    ((float4*)boxes_s)[(size_t)pair * KP + k] = bx;
    area_s[(size_t)pair * KP + k] = ar;
  }
  if (tid == 0) cnt_s[pair] = n_valid;
}

// ---------------------------------------------------------------------------
// kernel 3: suppression matrix. mat[pair][i][w] bit j-w*64 set iff
// IoU(box_i, box_j) > 0.5 and j > i.  Exactly mirrors reference arithmetic
// (incl. IEEE division) to be bit-identical.
// ---------------------------------------------------------------------------
__global__ __launch_bounds__(256) void k_iou(const float* __restrict__ boxes_s,
    const float* __restrict__ area_s, const int* __restrict__ cnt_s,
    u64* __restrict__ mat) {
  int pair = blockIdx.x, w = blockIdx.y;
  __shared__ float4 sbox[KNMS];
  __shared__ float sarea[KNMS];
  int cnt = cnt_s[pair];
  for (int i = threadIdx.x; i < KNMS; i += 256) {
    sbox[i] = ((const float4*)boxes_s)[(size_t)pair * KP + i];
    sarea[i] = area_s[(size_t)pair * KP + i];
  }
  __syncthreads();
  int lane = threadIdx.x & 63, wv = threadIdx.x >> 6;
  int j = w * 64 + lane;
  bool jok = j < KNMS;
  float4 bj = jok ? sbox[j] : make_float4(0.f, 0.f, 0.f, 0.f);
  float aj = jok ? sarea[j] : 0.f;
  u64* orow = mat + (size_t)pair * KP * 16 + w;
  int rowLim = cnt < (w * 64 + 63) ? cnt : (w * 64 + 63);
  for (int i = wv; i < rowLim; i += 4) {
    float4 bi = sbox[i]; float ai = sarea[i];
    float ltx = fmaxf(bi.x, bj.x), lty = fmaxf(bi.y, bj.y);
    float rbx = fminf(bi.z, bj.z), rby = fminf(bi.w, bj.w);
    float ww = fmaxf(rbx - ltx, 0.f), hh = fmaxf(rby - lty, 0.f);
    float inter = ww * hh;
    float uni = (ai + aj) - inter;
    float iou = inter / uni;                      // IEEE div, matches reference
    bool sup = jok && (j > i) && (iou > IOU_THR); // NaN -> false, matches jnp
    u64 word = __ballot(sup);
    if (lane == 0) orow[(size_t)i * 16] = word;
  }
  for (int i = rowLim + wv; i < cnt; i += 4)
    if (lane == 0) orow[(size_t)i * 16] = 0ull;
}

// ---------------------------------------------------------------------------
// kernel 4: serial greedy scan. 1 wave per pair; lanes 0..15 own keep-words.
// Register-group prefetch (16 rows ahead) hides load latency.
// ---------------------------------------------------------------------------
__global__ __launch_bounds__(64) void k_scan(const u64* __restrict__ mat,
    const int* __restrict__ cnt_s, u64* __restrict__ keep_out) {
  int pair = blockIdx.x;
  int lane = threadIdx.x;
  int cnt = cnt_s[pair];
  const u64* m = mat + (size_t)pair * KP * 16;
  u64 keepw = 0ull;
  if (lane < 16) {
    int nb = cnt - lane * 64;
    nb = nb < 0 ? 0 : (nb > 64 ? 64 : nb);
    keepw = (nb >= 64) ? ~0ull : ((nb > 0) ? ((1ull << nb) - 1ull) : 0ull);
  }
  bool ld = lane < 16;
  u64 cur[16], nxt[16];
#pragma unroll
  for (int r = 0; r < 16; r++) cur[r] = (ld && r < cnt) ? m[(size_t)r * 16 + lane] : 0ull;
  for (int g = 0; g < cnt; g += 16) {
#pragma unroll
    for (int r = 0; r < 16; r++) {
      int i = g + 16 + r;
      nxt[r] = (ld && i < cnt) ? m[(size_t)i * 16 + lane] : 0ull;
    }
#pragma unroll
    for (int r = 0; r < 16; r++) {
      int i = g + r;
      if (i < cnt) {
        u64 kw = __shfl(keepw, i >> 6);
        if ((kw >> (i & 63)) & 1ull) keepw &= ~cur[r];
      }
      cur[r] = nxt[r];
    }
  }
  if (lane < 16) keep_out[pair * 16 + lane] = keepw;
}

// ---------------------------------------------------------------------------
// kernel 5: per-batch stable top-mb over kept scores; write outputs.
// key = (score_bits << 32) | ~(c*KNMS + k)
// d_out = [rois B*mb*4][scores B*mb][class B*mb] all float32
// ---------------------------------------------------------------------------
__global__ __launch_bounds__(1024) void k_final(
    const float* __restrict__ scores_s, const float* __restrict__ boxes_s,
    const u64* __restrict__ keepm, float* __restrict__ out,
    int B, int C, int mb) {
  int b = blockIdx.x;
  int tid = threadIdx.x;
  __shared__ union { unsigned int hist[8192]; u64 cand[FCAP]; } sh;
  __shared__ unsigned int csum[1024];
  __shared__ unsigned int s_b1, s_gt1, s_tot1, s_b2, s_gt2, s_tot2;
  __shared__ int s_all1, s_all2, s_mode, s_n;

  for (int i = tid; i < 8192; i += 1024) sh.hist[i] = 0u;
  __syncthreads();
  int total_idx = C * KP;
  for (int idx = tid; idx < total_idx; idx += 1024) {
    int k = idx & (KP - 1);
    if (k >= KNMS) continue;
    int c = idx >> KPSH;
    int pair = b * C + c;
    float s = scores_s[(size_t)pair * KP + k];
    if (!(s > NEGINF)) continue;
    if (!((keepm[pair * 16 + (k >> 6)] >> (k & 63)) & 1ull)) continue;
    atomicAdd(&sh.hist[__float_as_uint(s) >> 18], 1u);
  }
  __syncthreads();
  find_cutoff(sh.hist, 8192, csum, 1024, tid, (unsigned)mb, &s_b1, &s_gt1, &s_tot1, &s_all1);
  unsigned b1 = s_b1, gt1 = s_gt1, tot = s_tot1;
  unsigned m1 = sh.hist[b1];
  if (tid == 0) s_mode = s_all1 ? 1 : 0;
  __syncthreads();
  if (s_mode == 0 && gt1 + m1 > FCAP) {
    for (int i = tid; i < 2048; i += 1024) sh.hist[i] = 0u;
    __syncthreads();
    for (int idx = tid; idx < total_idx; idx += 1024) {
      int k = idx & (KP - 1);
      if (k >= KNMS) continue;
      int c = idx >> KPSH;
      int pair = b * C + c;
      float s = scores_s[(size_t)pair * KP + k];
      if (!(s > NEGINF)) continue;
      if (!((keepm[pair * 16 + (k >> 6)] >> (k & 63)) & 1ull)) continue;
      unsigned bits = __float_as_uint(s);
      if ((bits >> 18) == b1) atomicAdd(&sh.hist[(bits >> 7) & 2047u], 1u);
    }
    __syncthreads();
    find_cutoff(sh.hist, 2048, csum, 1024, tid, (unsigned)mb - gt1, &s_b2, &s_gt2, &s_tot2, &s_all2);
    if (tid == 0) s_mode = 2;
    __syncthreads();
  }
  int mode = s_mode;
  unsigned b2v = (mode == 2 && !s_all2) ? s_b2 : 0u;
  if (tid == 0) s_n = 0;
  __syncthreads();
  for (int idx = tid; idx < total_idx; idx += 1024) {
    int k = idx & (KP - 1);
    if (k >= KNMS) continue;
    int c = idx >> KPSH;
    int pair = b * C + c;
    float s = scores_s[(size_t)pair * KP + k];
    if (!(s > NEGINF)) continue;
    if (!((keepm[pair * 16 + (k >> 6)] >> (k & 63)) & 1ull)) continue;
    unsigned bits = __float_as_uint(s);
    unsigned bin = bits >> 18;
    bool take = (mode == 1) || (mode == 0 ? (bin >= b1)
                : (bin > b1 || (bin == b1 && ((bits >> 7) & 2047u) >= b2v)));
    if (take) {
      int pos = atomicAdd(&s_n, 1);
      if (pos < FCAP)
        sh.cand[pos] = ((u64)bits << 32) | (unsigned)(~(unsigned)(c * KNMS + k));
    }
  }
  __syncthreads();
  int n = s_n < FCAP ? s_n : FCAP;
  for (int t = tid; t < FCAP; t += 1024)
    if (t >= n) sh.cand[t] = 0ull;
  __syncthreads();
  bitonic_desc<FCAP, 1024>((u64*)sh.cand, tid);

  int n_out = (int)tot < mb ? (int)tot : mb;
  for (int k = tid; k < mb; k += 1024) {
    u64 key = (k < FCAP) ? sh.cand[k] : 0ull;
    float4 bx = make_float4(0.f, 0.f, 0.f, 0.f);
    float sc = 0.f, cf = -1.f;
    if (k < n_out && key != 0ull) {
      sc = __uint_as_float((unsigned)(key >> 32));
      unsigned flat = ~(unsigned)key;
      int c = flat / KNMS;
      int kk = flat - c * KNMS;
      bx = ((const float4*)boxes_s)[(size_t)(b * C + c) * KP + kk];
      cf = (float)c;
    }
    size_t ro = (size_t)(b * mb + k) * 4;
    out[ro + 0] = bx.x; out[ro + 1] = bx.y; out[ro + 2] = bx.z; out[ro + 3] = bx.w;
    out[(size_t)B * mb * 4 + b * mb + k] = sc;
    out[(size_t)B * mb * 5 + b * mb + k] = cf;
  }
}

// ---------------------------------------------------------------------------
extern "C" void kernel_launch(void* const* d_in, const int* in_sizes, int n_in,
                              void* d_out, int out_size, void* d_ws, size_t ws_size,
                              hipStream_t stream) {
  const float* classification = (const float*)d_in[3];
  const float* tanch = (const float*)d_in[4];
  const float* thr_p = (const float*)d_in[5];

  int B = in_sizes[0] / (3 * 64 * 64);
  if (B <= 0) B = 4;
  long long BA = (long long)in_sizes[4] / 4;
  int A = (int)(BA / B);
  int C = (int)((long long)in_sizes[3] / BA);
  int NP = B * C;
  int mb = out_size / (B * 6);

  auto rsz = [](size_t x) { return (x + 255) & ~(size_t)255; };
  size_t clsT_bytes = rsz((size_t)NP * A * 4);
  size_t rest = rsz((size_t)NP * KP * 4)       // scores
              + rsz((size_t)NP * KP * 16)      // boxes
              + rsz((size_t)NP * KP * 4)       // areas
              + rsz((size_t)NP * 4)            // counts
              + rsz((size_t)NP * KP * 16 * 8)  // suppression matrix
              + rsz((size_t)NP * 16 * 8);      // keep masks
  int use_t = (C <= 127 && ws_size >= rest + clsT_bytes) ? 1 : 0;

  size_t off = 0;
  auto take = [&](size_t bytes) {
    void* p = (char*)d_ws + off;
    off += rsz(bytes);
    return p;
  };
  float* clsT = nullptr;
  if (use_t) clsT = (float*)take((size_t)NP * A * 4);
  float* scores_s = (float*)take((size_t)NP * KP * 4);
  float* boxes_s  = (float*)take((size_t)NP * KP * 16);
  float* area_s   = (float*)take((size_t)NP * KP * 4);
  int*   cnt_s    = (int*)take((size_t)NP * 4);
  u64*   mat      = (u64*)take((size_t)NP * KP * 16 * 8);
  u64*   keepm    = (u64*)take((size_t)NP * 16 * 8);

  if (use_t)
    k_transpose<<<dim3((A + 63) / 64, B), 256, 0, stream>>>(classification, clsT, A, C);
  k_topk<<<NP, 512, 0, stream>>>(use_t ? clsT : classification, use_t, tanch, thr_p,
                                 scores_s, boxes_s, area_s, cnt_s, A, C);
  k_iou<<<dim3(NP, 16), 256, 0, stream>>>(boxes_s, area_s, cnt_s, mat);
  k_scan<<<NP, 64, 0, stream>>>(mat, cnt_s, keepm);
  k_final<<<B, 1024, 0, stream>>>(scores_s, boxes_s, keepm, (float*)d_out, B, C, mb);
}